// Round 27
// baseline (104.061 us; speedup 1.0000x reference)
//
#include <hip/hip_runtime.h>

// Problem constants (B=2, N=2048, d_model=1024, H=16, D=64)
#define DMODEL 1024
#define NSEQ   2048
#define BSZ    2
#define NH     16
#define HD     64
#define MROWS  (BSZ*NSEQ)   // 4096

using short8 = __attribute__((ext_vector_type(8))) short;
using f32x4  = __attribute__((ext_vector_type(4))) float;

__device__ __forceinline__ short f2b(float f) {
  unsigned u = __builtin_bit_cast(unsigned, f);
  u += 0x7fffu + ((u >> 16) & 1u);          // RNE
  return (short)(u >> 16);
}

__device__ __forceinline__ void load_lds16(const void* g, void* l) {
  __builtin_amdgcn_global_load_lds((const __attribute__((address_space(1))) unsigned int*)g,
                                   (__attribute__((address_space(3))) unsigned int*)l,
                                   16, 0, 0);
}

// ---------------- fused fp32->bf16 conversion (x, 4 weights) + RoPE table ----------------
__global__ void cvt_all(const float* __restrict__ x,  const float* __restrict__ Wq,
                        const float* __restrict__ Wk, const float* __restrict__ Wv,
                        const float* __restrict__ Wo, const int* __restrict__ pos,
                        short* __restrict__ xb,  short* __restrict__ wqb,
                        short* __restrict__ wkb, short* __restrict__ wvb,
                        short* __restrict__ wob, float* __restrict__ cs) {
  const int NX  = (BSZ * NSEQ * DMODEL) / 4;   // 1,048,576 float4s
  const int NW  = (DMODEL * DMODEL) / 4;       // 262,144 = 2^18
  const int NCV = NX + 4 * NW;
  const int TOT = NCV + NSEQ * 32;
  for (int i = blockIdx.x * blockDim.x + threadIdx.x; i < TOT; i += gridDim.x * blockDim.x) {
    if (i < NCV) {
      const float* src; short* dst; int off;
      if (i < NX) { src = x; dst = xb; off = i; }
      else {
        int j = i - NX; int s = j >> 18; off = j & (NW - 1);
        src = (s == 0) ? Wq : (s == 1) ? Wk : (s == 2) ? Wv : Wo;
        dst = (s == 0) ? wqb : (s == 1) ? wkb : (s == 2) ? wvb : wob;
      }
      float4 v = reinterpret_cast<const float4*>(src)[off];
      short4 r;
      r.x = f2b(v.x); r.y = f2b(v.y); r.z = f2b(v.z); r.w = f2b(v.w);
      reinterpret_cast<short4*>(dst)[off] = r;
    } else {
      int idx = i - NCV;
      int n = idx >> 5, p = idx & 31;
      float inv = powf(10000.0f, -(float)(2 * p) / 64.0f);
      float ang = (float)pos[n] * inv;
      cs[idx * 2]     = cosf(ang);
      cs[idx * 2 + 1] = sinf(ang);
    }
  }
}

// ============ Fused QKV projection: 128x64 tiles, 3-buffer ring, 1 barrier/iter ============
// Grid 512 = 32 row-panels (id&31 -> XCD keeps 4 A-panels L2-local) x 16 col-panels.
// 8 waves (2 row-groups x 4 col-groups): wave = 64 rows x 16 cols x {Q,K,V}.
// Ring: {STAGE(kt+1 -> nxt); vmcnt(5); barrier; compute(cur)} — buf b read at
// iter b is restaged at iter b+2, one full barrier apart (validated pattern).
// LDS 120KB: A[3][128][64], B[3][3][64][64]. Q pre-scaled by (1/8)*log2e.
__global__ __launch_bounds__(512, 1) void gemm_qkv3(
    const short* __restrict__ xb,
    const short* __restrict__ wq, const short* __restrict__ wk, const short* __restrict__ wv,
    const float* __restrict__ cs,
    short* __restrict__ qb, short* __restrict__ kb, short* __restrict__ vt) {
  __shared__ short Al[3][128 * 64];     // 3 x 16KB
  __shared__ short Bl[3][3][64 * 64];   // 3 x 24KB

  const int t   = threadIdx.x;
  const int l   = t & 63;
  const int wid = t >> 6;            // 0..7
  const int wr  = (wid >> 2) * 64;   // wave row-offset: 0 / 64
  const int wc  = (wid & 3) * 16;    // wave col-offset: 0..48

  const int id = blockIdx.x;         // 0..511; id&7 -> XCD (bx&7): A panels L2-local
  const int bx = id & 31;
  const int np = id >> 5;            // 0..15
  const int arow0 = bx * 128;
  const int bcol0 = np * 64;

  const int tr = t >> 3;             // 0..63
  const int c8 = (t & 7) ^ ((t >> 3) & 7);
  const short* W3[3] = {wq, wk, wv};

  auto STAGE = [&](int kt, int buf) {  // 5 loads/thread: A h0,h1 + 3 weights
#pragma unroll
    for (int h = 0; h < 2; ++h)
      load_lds16(xb + (size_t)(arow0 + h * 64 + tr) * DMODEL + kt * 64 + c8 * 8,
                 &Al[buf][h * 4096 + wid * 512]);
#pragma unroll
    for (int p = 0; p < 3; ++p)
      load_lds16(W3[p] + (size_t)(bcol0 + tr) * DMODEL + kt * 64 + c8 * 8,
                 &Bl[buf][p][wid * 512]);
  };

  f32x4 acc[3][4];
#pragma unroll
  for (int p = 0; p < 3; ++p)
#pragma unroll
    for (int mi = 0; mi < 4; ++mi) acc[p][mi] = f32x4{0.f, 0.f, 0.f, 0.f};

  const int lr  = l & 15;
  const int lcb = (l >> 4) << 4;

  STAGE(0, 0);
  int cur = 0;

  for (int kt = 0; kt < DMODEL / 64; ++kt) {
    const int nxt = (cur == 2) ? 0 : cur + 1;
    if (kt + 1 < DMODEL / 64) {
      STAGE(kt + 1, nxt);                              // 5 newer loads in flight
      asm volatile("s_waitcnt vmcnt(5)" ::: "memory"); // buf[cur]'s 5 landed
    } else {
      asm volatile("s_waitcnt vmcnt(0)" ::: "memory");
    }
    asm volatile("s_barrier" ::: "memory");            // all waves' buf[cur] ready

    const char* Ab = reinterpret_cast<const char*>(&Al[cur][0]);
#pragma unroll
    for (int ks = 0; ks < 2; ++ks) {
      const int cb = ks * 64 + lcb;
      short8 af[4];
#pragma unroll
      for (int mi = 0; mi < 4; ++mi) {
        int r = wr + mi * 16 + lr;
        af[mi] = *reinterpret_cast<const short8*>(Ab + r * 128 + (cb ^ ((r & 7) << 4)));
      }
#pragma unroll
      for (int p = 0; p < 3; ++p) {
        const char* Bb = reinterpret_cast<const char*>(&Bl[cur][p][0]);
        int r = wc + lr;
        short8 bf = *reinterpret_cast<const short8*>(Bb + r * 128 + (cb ^ ((r & 7) << 4)));
#pragma unroll
        for (int mi = 0; mi < 4; ++mi)
          acc[p][mi] = __builtin_amdgcn_mfma_f32_16x16x32_bf16(af[mi], bf, acc[p][mi], 0, 0, 0);
      }
    }
    cur = nxt;
  }

  // ---------- epilogue: RoPE + scatter for Q,K; transpose-scatter V
  const int irow = (l >> 4) << 2;
#pragma unroll
  for (int p = 0; p < 3; ++p) {
#pragma unroll
    for (int mi = 0; mi < 4; ++mi) {
#pragma unroll
      for (int r = 0; r < 4; ++r) {
        float v = acc[p][mi][r];
        int m = arow0 + wr + mi * 16 + irow + r;
        int j = bcol0 + wc + (l & 15);
        int n = m & (NSEQ - 1);
        int b = m >> 11;
        int h = j >> 6, d = j & 63, pp = d >> 1;
        float pv = __shfl_xor(v, 1);              // partner column (j^1), same row
        if (p < 2) {
          float c = cs[(n * 32 + pp) * 2];
          float s = cs[(n * 32 + pp) * 2 + 1];
          float res = (d & 1) ? (pv * s + v * c) : (v * c - pv * s);
          if (p == 0) res *= 0.180336880f;        // (1/sqrt(64)) * log2(e): P = exp2(S)
          short* dst = (p == 0) ? qb : kb;
          dst[(((size_t)(b * NH + h)) * NSEQ + n) * HD + d] = f2b(res);
        } else {
          vt[(((size_t)(b * NH + h)) * HD + d) * NSEQ + n] = f2b(v);
        }
      }
    }
  }
}

// ---------------- output projection: 64x128 tiles, 3-buffer ring, 1 barrier/iter ----------------
__global__ __launch_bounds__(256, 2) void gemm_out(
    const short* __restrict__ ob, const short* __restrict__ wo, float* __restrict__ out) {
  __shared__ short As[3 * 64 * 64];    // [3][4096] shorts, rows 128B
  __shared__ short Bs[3 * 128 * 64];   // [3][8192] shorts, rows 128B
  const int t = threadIdx.x;
  const int l = t & 63;
  const int w4 = t >> 6;               // 0..3
  const int wrow = (w4 >> 1) * 32;
  const int wcol = (w4 & 1) * 64;
  const int id = blockIdx.x;           // id&7 -> XCD: 8 row-panels/XCD (A L2-local)
  const int arow0 = (id & 63) * 64;
  const int bcol0 = (id >> 6) * 128;

  const int tr = t >> 3;               // 0..31
  const int c8 = (t & 7) ^ (tr & 7);   // rows step by 32 -> row&7 invariant

  auto STAGE = [&](int kt, int buf) {  // 6 loads/thread: A x2 + B x4
#pragma unroll
    for (int is = 0; is < 2; ++is)
      load_lds16(ob + (size_t)(arow0 + tr + is * 32) * DMODEL + kt * 64 + c8 * 8,
                 &As[buf * 4096 + is * 2048 + (t >> 6) * 512]);
#pragma unroll
    for (int is = 0; is < 4; ++is)
      load_lds16(wo + (size_t)(bcol0 + tr + is * 32) * DMODEL + kt * 64 + c8 * 8,
                 &Bs[buf * 8192 + is * 2048 + (t >> 6) * 512]);
  };

  f32x4 acc[2][4];
#pragma unroll
  for (int mi = 0; mi < 2; ++mi)
#pragma unroll
    for (int ni = 0; ni < 4; ++ni) acc[mi][ni] = f32x4{0.f, 0.f, 0.f, 0.f};

  const int lr  = l & 15;
  const int lcb = (l >> 4) << 4;
  const int irow = (l >> 4) << 2;

  STAGE(0, 0);
  int cur = 0;

  for (int kt = 0; kt < DMODEL / 64; ++kt) {
    const int nxt = (cur == 2) ? 0 : cur + 1;
    if (kt + 1 < DMODEL / 64) {
      STAGE(kt + 1, nxt);                              // 6 newer loads in flight
      asm volatile("s_waitcnt vmcnt(6)" ::: "memory"); // buf[cur]'s 6 landed
    } else {
      asm volatile("s_waitcnt vmcnt(0)" ::: "memory");
    }
    asm volatile("s_barrier" ::: "memory");            // all waves' buf[cur] ready

    const char* Ab = reinterpret_cast<const char*>(&As[cur * 4096]);
    const char* Bb = reinterpret_cast<const char*>(&Bs[cur * 8192]);
#pragma unroll
    for (int ks = 0; ks < 2; ++ks) {
      const int cb = ks * 64 + lcb;
      short8 af[2], bf[4];
#pragma unroll
      for (int mi = 0; mi < 2; ++mi) {
        int r = wrow + mi * 16 + lr;
        af[mi] = *reinterpret_cast<const short8*>(Ab + r * 128 + (cb ^ ((r & 7) << 4)));
      }
#pragma unroll
      for (int ni = 0; ni < 4; ++ni) {
        int r = wcol + ni * 16 + lr;
        bf[ni] = *reinterpret_cast<const short8*>(Bb + r * 128 + (cb ^ ((r & 7) << 4)));
      }
#pragma unroll
      for (int mi = 0; mi < 2; ++mi)
#pragma unroll
        for (int ni = 0; ni < 4; ++ni)
          acc[mi][ni] = __builtin_amdgcn_mfma_f32_16x16x32_bf16(af[mi], bf[ni], acc[mi][ni], 0, 0, 0);
    }
    cur = nxt;
  }

#pragma unroll
  for (int mi = 0; mi < 2; ++mi) {
#pragma unroll
    for (int ni = 0; ni < 4; ++ni) {
#pragma unroll
      for (int r = 0; r < 4; ++r) {
        int m = arow0 + wrow + mi * 16 + irow + r;
        int j = bcol0 + wcol + ni * 16 + (l & 15);
        out[(size_t)m * DMODEL + j] = acc[mi][ni][r];
      }
    }
  }
}

// ---------------- flash attention: QBLK=128, KVBLK=128, 16 waves, 3-buffer ring ----------------
// waves = (qs 0..7: 16-row q-strip) x (g 0..1: 64-key half). Fixed-shift softmax.
// ONE barrier/iter with 3-deep ring. LDS 128KB: K[3][128][64], V[3][64][128], P[16][16][64].
__global__ __launch_bounds__(1024, 1) void attn(
    const short* __restrict__ qb, const short* __restrict__ kb,
    const short* __restrict__ vt, short* __restrict__ ob) {
  __shared__ short Ks[3][128 * 64];
  __shared__ short Vs[3][64 * 128];
  __shared__ short Ps[16][16 * 64];
  const int t = threadIdx.x;
  const int l = t & 63;
  const int w = t >> 6;                 // 0..15
  const int qs = w & 7;                 // q strip (16 rows)
  const int g  = w >> 3;                // key group (64-key half)
  const int id  = blockIdx.x;
  const int xcd = id & 7;
  const int bh  = xcd + 8 * (id >> 6);  // 4 heads per XCD
  const int qy  = (id >> 3) & 7;        // fold pair index 0..7
  const short* Q  = qb + (size_t)bh * NSEQ * HD;
  const short* Kg = kb + (size_t)bh * NSEQ * HD;
  const short* Vg = vt + (size_t)bh * HD * NSEQ;
  const int b = bh >> 4, h = bh & 15;

  const int trk = t >> 3;               // K staging row 0..127
  const int ck  = (t & 7) ^ ((t >> 3) & 7);
  const int trv = t >> 4;               // V staging row 0..63
  const int cv  = (t & 15) ^ ((t >> 4) & 15);
  const int irow = (l >> 4) << 2;
  const short8 ones = {(short)0x3F80, (short)0x3F80, (short)0x3F80, (short)0x3F80,
                       (short)0x3F80, (short)0x3F80, (short)0x3F80, (short)0x3F80};

  auto STAGEA = [&](int tile, int buf) {   // 2 loads/thread (1024 thr cover K+V)
    int j0 = tile * 128;
    load_lds16(Kg + (size_t)(j0 + trk) * HD + ck * 8, &Ks[buf][t * 8]);
    load_lds16(Vg + (size_t)trv * NSEQ + j0 + cv * 8, &Vs[buf][t * 8]);
  };

  int cur = 0;
  for (int pass = 0; pass < 2; ++pass) {
    const int qt = pass ? (15 - qy) : qy;     // q-tile of 128 rows
    const int q0 = qt * 128;
    const int nt = qt + 1;                    // 128-key tiles this pass

    asm volatile("s_barrier" ::: "memory");   // scratch + ring free before restage
    STAGEA(0, cur);

    short8 qf[2];
    {
      int qrow = q0 + qs * 16 + (l & 15);
#pragma unroll
      for (int ks = 0; ks < 2; ++ks)
        qf[ks] = *reinterpret_cast<const short8*>(Q + (size_t)qrow * HD + ks * 32 + (l >> 4) * 8);
    }

    f32x4 ao[4];
#pragma unroll
    for (int dt = 0; dt < 4; ++dt) ao[dt] = f32x4{0.f, 0.f, 0.f, 0.f};
    f32x4 accl = f32x4{0.f, 0.f, 0.f, 0.f};

    for (int tile = 0; tile < nt; ++tile) {
      const int nxt = (cur == 2) ? 0 : cur + 1;
      if (tile + 1 < nt) {
        STAGEA(tile + 1, nxt);
        asm volatile("s_waitcnt vmcnt(2)" ::: "memory");   // buf[cur]'s 2 landed
      } else {
        asm volatile("s_waitcnt vmcnt(0)" ::: "memory");
      }
      asm volatile("s_barrier" ::: "memory");              // all waves' buf[cur] ready

      const char* Kb = reinterpret_cast<const char*>(&Ks[cur][0]);
      const char* Vb = reinterpret_cast<const char*>(&Vs[cur][0]);

      // S = Q K^T over this wave's 64-key half (log2 domain via Q pre-scale)
      f32x4 sc[4];
#pragma unroll
      for (int jt = 0; jt < 4; ++jt) sc[jt] = f32x4{0.f, 0.f, 0.f, 0.f};
#pragma unroll
      for (int ks = 0; ks < 2; ++ks) {
        const int cb = ks * 64 + ((l >> 4) * 16);
#pragma unroll
        for (int jt = 0; jt < 4; ++jt) {
          int kr = g * 64 + jt * 16 + (l & 15);
          short8 kf = *reinterpret_cast<const short8*>(Kb + kr * 128 + (cb ^ ((kr & 7) << 4)));
          sc[jt] = __builtin_amdgcn_mfma_f32_16x16x32_bf16(qf[ks], kf, sc[jt], 0, 0, 0);
        }
      }

      if (tile == nt - 1) {                 // diagonal tile: mask j_g > i_g
        const int j0 = tile * 128 + g * 64;
#pragma unroll
        for (int jt = 0; jt < 4; ++jt)
#pragma unroll
          for (int r = 0; r < 4; ++r) {
            int i_g = q0 + qs * 16 + irow + r;
            int j_g = j0 + jt * 16 + (l & 15);
            if (j_g > i_g) sc[jt][r] = -1e30f;
          }
      }

      // P = exp2(S), bf16 truncate, to per-wave swizzled LDS [16][64]
#pragma unroll
      for (int jt = 0; jt < 4; ++jt) {
#pragma unroll
        for (int r = 0; r < 4; ++r) {
          float p = __builtin_amdgcn_exp2f(sc[jt][r]);
          int i = irow + r;
          int jj = jt * 16 + (l & 15);
          Ps[w][i * 64 + (jj ^ ((i & 7) << 3))] =
              (short)(__builtin_bit_cast(unsigned, p) >> 16);
        }
      }

      // O += P*V ; row-sum += P*ones  (64 keys = 2 slices of 32)
#pragma unroll
      for (int ks2 = 0; ks2 < 2; ++ks2) {
        const int cb = ks2 * 64 + ((l >> 4) * 16);
        int pr = l & 15;
        short8 pf = *reinterpret_cast<const short8*>(
            reinterpret_cast<const char*>(&Ps[w][0]) + pr * 128 + (cb ^ ((pr & 7) << 4)));
        accl = __builtin_amdgcn_mfma_f32_16x16x32_bf16(pf, ones, accl, 0, 0, 0);
#pragma unroll
        for (int dt = 0; dt < 4; ++dt) {
          int vr = dt * 16 + (l & 15);
          short8 vf = *reinterpret_cast<const short8*>(
              Vb + vr * 256 + ((g * 128 + cb) ^ ((vr & 15) << 4)));
          ao[dt] = __builtin_amdgcn_mfma_f32_16x16x32_bf16(pf, vf, ao[dt], 0, 0, 0);
        }
      }
      cur = nxt;
    }
    asm volatile("s_barrier" ::: "memory");   // all waves done reading the ring

    // ---- cross-group reduction (fixed-shift: partials just add) ----
    float* Opart = reinterpret_cast<float*>(&Ks[0][0]);
    float* Apart = reinterpret_cast<float*>(&Vs[0][0]);   // 8 x 16 f32
    const int cswz = ((l >> 4) & 1) << 4;
    if (g == 1) {
#pragma unroll
      for (int dt = 0; dt < 4; ++dt)
#pragma unroll
        for (int r = 0; r < 4; ++r)
          Opart[qs * 1024 + (irow + r) * 64 + ((dt * 16 + (l & 15)) ^ cswz)] = ao[dt][r];
      if ((l & 15) == 0)
#pragma unroll
        for (int r = 0; r < 4; ++r)
          Apart[qs * 16 + irow + r] = accl[r];
    }
    asm volatile("s_barrier" ::: "memory");
    if (g == 0) {
#pragma unroll
      for (int dt = 0; dt < 4; ++dt)
#pragma unroll
        for (int r = 0; r < 4; ++r)
          ao[dt][r] += Opart[qs * 1024 + (irow + r) * 64 + ((dt * 16 + (l & 15)) ^ cswz)];
#pragma unroll
      for (int r = 0; r < 4; ++r)
        accl[r] += Apart[qs * 16 + irow + r];
#pragma unroll
      for (int dt = 0; dt < 4; ++dt)
#pragma unroll
        for (int r = 0; r < 4; ++r) {
          int n = q0 + qs * 16 + irow + r;
          int col = h * 64 + dt * 16 + (l & 15);
          ob[((size_t)b * NSEQ + n) * DMODEL + col] = f2b(ao[dt][r] / accl[r]);
        }
    }
  }
}

// ---------------- launch ----------------
extern "C" void kernel_launch(void* const* d_in, const int* in_sizes, int n_in,
                              void* d_out, int out_size, void* d_ws, size_t ws_size,
                              hipStream_t stream) {
  const float* x  = (const float*)d_in[0];
  const float* Wq = (const float*)d_in[1];
  const float* Wk = (const float*)d_in[2];
  const float* Wv = (const float*)d_in[3];
  const float* Wo = (const float*)d_in[4];
  const int*   pos = (const int*)d_in[5];
  float* out = (float*)d_out;
  char* ws = (char*)d_ws;

  short* xb  = (short*)(ws);
  short* wqb = (short*)(ws + ((size_t)8  << 20));
  short* wkb = (short*)(ws + ((size_t)10 << 20));
  short* wvb = (short*)(ws + ((size_t)12 << 20));
  short* wob = (short*)(ws + ((size_t)14 << 20));
  short* qb  = (short*)(ws + ((size_t)16 << 20));
  short* kb  = (short*)(ws + ((size_t)24 << 20));
  short* vt  = (short*)(ws + ((size_t)32 << 20));
  short* ob  = (short*)(ws + ((size_t)40 << 20));
  float* cs  = (float*)(ws + ((size_t)48 << 20));

  cvt_all<<<2048, 256, 0, stream>>>(x, Wq, Wk, Wv, Wo, pos, xb, wqb, wkb, wvb, wob, cs);
  gemm_qkv3<<<512, 512, 0, stream>>>(xb, wqb, wkb, wvb, cs, qb, kb, vt);
  attn<<<256, 1024, 0, stream>>>(qb, kb, vt, ob);
  gemm_out<<<512, 256, 0, stream>>>(ob, wob, out);
}

// Round 28
// 92.656 us; speedup vs baseline: 1.1231x; 1.1231x over previous
//
#include <hip/hip_runtime.h>

// Problem constants (B=2, N=2048, d_model=1024, H=16, D=64)
#define DMODEL 1024
#define NSEQ   2048
#define BSZ    2
#define NH     16
#define HD     64
#define MROWS  (BSZ*NSEQ)   // 4096

using short8 = __attribute__((ext_vector_type(8))) short;
using f32x4  = __attribute__((ext_vector_type(4))) float;

__device__ __forceinline__ short f2b(float f) {
  unsigned u = __builtin_bit_cast(unsigned, f);
  u += 0x7fffu + ((u >> 16) & 1u);          // RNE
  return (short)(u >> 16);
}

__device__ __forceinline__ void load_lds16(const void* g, void* l) {
  __builtin_amdgcn_global_load_lds((const __attribute__((address_space(1))) unsigned int*)g,
                                   (__attribute__((address_space(3))) unsigned int*)l,
                                   16, 0, 0);
}

// ---------------- fused fp32->bf16 conversion (x, 4 weights) + RoPE table ----------------
__global__ void cvt_all(const float* __restrict__ x,  const float* __restrict__ Wq,
                        const float* __restrict__ Wk, const float* __restrict__ Wv,
                        const float* __restrict__ Wo, const int* __restrict__ pos,
                        short* __restrict__ xb,  short* __restrict__ wqb,
                        short* __restrict__ wkb, short* __restrict__ wvb,
                        short* __restrict__ wob, float* __restrict__ cs) {
  const int NX  = (BSZ * NSEQ * DMODEL) / 4;   // 1,048,576 float4s
  const int NW  = (DMODEL * DMODEL) / 4;       // 262,144 = 2^18
  const int NCV = NX + 4 * NW;
  const int TOT = NCV + NSEQ * 32;
  for (int i = blockIdx.x * blockDim.x + threadIdx.x; i < TOT; i += gridDim.x * blockDim.x) {
    if (i < NCV) {
      const float* src; short* dst; int off;
      if (i < NX) { src = x; dst = xb; off = i; }
      else {
        int j = i - NX; int s = j >> 18; off = j & (NW - 1);
        src = (s == 0) ? Wq : (s == 1) ? Wk : (s == 2) ? Wv : Wo;
        dst = (s == 0) ? wqb : (s == 1) ? wkb : (s == 2) ? wvb : wob;
      }
      float4 v = reinterpret_cast<const float4*>(src)[off];
      short4 r;
      r.x = f2b(v.x); r.y = f2b(v.y); r.z = f2b(v.z); r.w = f2b(v.w);
      reinterpret_cast<short4*>(dst)[off] = r;
    } else {
      int idx = i - NCV;
      int n = idx >> 5, p = idx & 31;
      float inv = powf(10000.0f, -(float)(2 * p) / 64.0f);
      float ang = (float)pos[n] * inv;
      cs[idx * 2]     = cosf(ang);
      cs[idx * 2 + 1] = sinf(ang);
    }
  }
}

// ============ Fused QKV projection: A staged once, 3 weight tiles ============
// Q is pre-scaled by (1/8)*log2e so attn computes P = exp2(S) directly.
__global__ __launch_bounds__(512, 1) void gemm_qkv3(
    const short* __restrict__ xb,
    const short* __restrict__ wq, const short* __restrict__ wk, const short* __restrict__ wv,
    const float* __restrict__ cs,
    short* __restrict__ qb, short* __restrict__ kb, short* __restrict__ vt) {
  __shared__ short Al[2][128 * 64];
  __shared__ short Bl[2][3][128 * 64];

  const int t   = threadIdx.x;
  const int l   = t & 63;
  const int wid = t >> 6;            // 0..7
  const int wr  = (wid >> 2) * 64;   // wave row-offset: 0 / 64
  const int wc  = (wid & 3) * 32;    // wave col-offset: 0..96

  const int id = blockIdx.x;         // id&7 == bx&7 -> XCD owns 4 A-panels
  const int bx = id & 31;
  const int np = id >> 5;            // 0..7
  const int arow0 = bx * 128;
  const int bcol0 = np * 128;

  const int tr = t >> 3;
  const int c8 = (t & 7) ^ ((t >> 3) & 7);
  const short* W3[3] = {wq, wk, wv};

  auto STAGE = [&](int kt, int buf) {  // 8 loads/thread: A h0,h1 + 3p x 2h
#pragma unroll
    for (int h = 0; h < 2; ++h)
      load_lds16(xb + (size_t)(arow0 + h * 64 + tr) * DMODEL + kt * 64 + c8 * 8,
                 &Al[buf][h * 4096 + wid * 512]);
#pragma unroll
    for (int p = 0; p < 3; ++p)
#pragma unroll
      for (int h = 0; h < 2; ++h)
        load_lds16(W3[p] + (size_t)(bcol0 + h * 64 + tr) * DMODEL + kt * 64 + c8 * 8,
                   &Bl[buf][p][h * 4096 + wid * 512]);
  };

  f32x4 acc[3][4][2];
#pragma unroll
  for (int p = 0; p < 3; ++p)
#pragma unroll
    for (int mi = 0; mi < 4; ++mi)
#pragma unroll
      for (int ni = 0; ni < 2; ++ni) acc[p][mi][ni] = f32x4{0.f, 0.f, 0.f, 0.f};

  const int lr  = l & 15;
  const int lcb = (l >> 4) << 4;

  STAGE(0, 0);
  int cur = 0;

  for (int kt = 0; kt < DMODEL / 64; ++kt) {
    if (kt + 1 < DMODEL / 64) {
      STAGE(kt + 1, cur ^ 1);                          // 8 newer loads in flight
      asm volatile("s_waitcnt vmcnt(8)" ::: "memory"); // tile kt's 8 landed
    } else {
      asm volatile("s_waitcnt vmcnt(0)" ::: "memory");
    }
    asm volatile("s_barrier" ::: "memory");            // publish buf[cur]

    const char* Ab = reinterpret_cast<const char*>(&Al[cur][0]);
#pragma unroll
    for (int ks = 0; ks < 2; ++ks) {
      const int cb = ks * 64 + lcb;
      short8 af[4];
#pragma unroll
      for (int mi = 0; mi < 4; ++mi) {
        int r = wr + mi * 16 + lr;
        af[mi] = *reinterpret_cast<const short8*>(Ab + r * 128 + (cb ^ ((r & 7) << 4)));
      }
#pragma unroll
      for (int p = 0; p < 3; ++p) {
        const char* Bb = reinterpret_cast<const char*>(&Bl[cur][p][0]);
        short8 bf[2];
#pragma unroll
        for (int ni = 0; ni < 2; ++ni) {
          int r = wc + ni * 16 + lr;
          bf[ni] = *reinterpret_cast<const short8*>(Bb + r * 128 + (cb ^ ((r & 7) << 4)));
        }
#pragma unroll
        for (int mi = 0; mi < 4; ++mi)
#pragma unroll
          for (int ni = 0; ni < 2; ++ni)
            acc[p][mi][ni] = __builtin_amdgcn_mfma_f32_16x16x32_bf16(af[mi], bf[ni], acc[p][mi][ni], 0, 0, 0);
      }
    }
    asm volatile("s_barrier" ::: "memory");            // reads done before next overwrite
    cur ^= 1;
  }

  // ---------- epilogue: RoPE + scatter for Q,K; transpose-scatter V
#pragma unroll
  for (int p = 0; p < 3; ++p) {
#pragma unroll
    for (int mi = 0; mi < 4; ++mi) {
#pragma unroll
      for (int ni = 0; ni < 2; ++ni) {
#pragma unroll
        for (int r = 0; r < 4; ++r) {
          float v = acc[p][mi][ni][r];
          int m = arow0 + wr + mi * 16 + ((l >> 4) << 2) + r;
          int j = bcol0 + wc + ni * 16 + (l & 15);
          int n = m & (NSEQ - 1);
          int b = m >> 11;
          int h = j >> 6, d = j & 63, pp = d >> 1;
          float pv = __shfl_xor(v, 1);              // partner column (j^1), same row
          if (p < 2) {
            float c = cs[(n * 32 + pp) * 2];
            float s = cs[(n * 32 + pp) * 2 + 1];
            float res = (d & 1) ? (pv * s + v * c) : (v * c - pv * s);
            if (p == 0) res *= 0.180336880f;        // (1/sqrt(64)) * log2(e): P = exp2(S)
            short* dst = (p == 0) ? qb : kb;
            dst[(((size_t)(b * NH + h)) * NSEQ + n) * HD + d] = f2b(res);
          } else {
            vt[(((size_t)(b * NH + h)) * HD + d) * NSEQ + n] = f2b(v);
          }
        }
      }
    }
  }
}

// ---------------- output projection: 64x128 tiles, 3-buffer ring, 1 barrier/iter ----------------
// 512 blocks = 2 blocks/CU (72KB LDS each). {STAGE(kt+1 -> nxt); vmcnt(6);
// barrier; compute(cur)}: vmcnt certifies own stage of buf[cur]; barrier all
// waves'; buf[b] read at iter i next written at i+2 (one full barrier apart).
__global__ __launch_bounds__(256, 2) void gemm_out(
    const short* __restrict__ ob, const short* __restrict__ wo, float* __restrict__ out) {
  __shared__ short As[3 * 64 * 64];    // [3][4096] shorts, rows 128B
  __shared__ short Bs[3 * 128 * 64];   // [3][8192] shorts, rows 128B
  const int t = threadIdx.x;
  const int l = t & 63;
  const int w4 = t >> 6;               // 0..3
  const int wrow = (w4 >> 1) * 32;
  const int wcol = (w4 & 1) * 64;
  const int id = blockIdx.x;           // id&7 -> XCD: 8 row-panels/XCD (A L2-local)
  const int arow0 = (id & 63) * 64;
  const int bcol0 = (id >> 6) * 128;

  const int tr = t >> 3;               // 0..31
  const int c8 = (t & 7) ^ (tr & 7);   // rows step by 32 -> row&7 invariant

  auto STAGE = [&](int kt, int buf) {  // 6 loads/thread: A x2 + B x4
#pragma unroll
    for (int is = 0; is < 2; ++is)
      load_lds16(ob + (size_t)(arow0 + tr + is * 32) * DMODEL + kt * 64 + c8 * 8,
                 &As[buf * 4096 + is * 2048 + (t >> 6) * 512]);
#pragma unroll
    for (int is = 0; is < 4; ++is)
      load_lds16(wo + (size_t)(bcol0 + tr + is * 32) * DMODEL + kt * 64 + c8 * 8,
                 &Bs[buf * 8192 + is * 2048 + (t >> 6) * 512]);
  };

  f32x4 acc[2][4];
#pragma unroll
  for (int mi = 0; mi < 2; ++mi)
#pragma unroll
    for (int ni = 0; ni < 4; ++ni) acc[mi][ni] = f32x4{0.f, 0.f, 0.f, 0.f};

  const int lr  = l & 15;
  const int lcb = (l >> 4) << 4;
  const int irow = (l >> 4) << 2;

  STAGE(0, 0);
  int cur = 0;

  for (int kt = 0; kt < DMODEL / 64; ++kt) {
    const int nxt = (cur == 2) ? 0 : cur + 1;
    if (kt + 1 < DMODEL / 64) {
      STAGE(kt + 1, nxt);                              // 6 newer loads in flight
      asm volatile("s_waitcnt vmcnt(6)" ::: "memory"); // buf[cur]'s 6 landed
    } else {
      asm volatile("s_waitcnt vmcnt(0)" ::: "memory");
    }
    asm volatile("s_barrier" ::: "memory");            // all waves' buf[cur] ready

    const char* Ab = reinterpret_cast<const char*>(&As[cur * 4096]);
    const char* Bb = reinterpret_cast<const char*>(&Bs[cur * 8192]);
#pragma unroll
    for (int ks = 0; ks < 2; ++ks) {
      const int cb = ks * 64 + lcb;
      short8 af[2], bf[4];
#pragma unroll
      for (int mi = 0; mi < 2; ++mi) {
        int r = wrow + mi * 16 + lr;
        af[mi] = *reinterpret_cast<const short8*>(Ab + r * 128 + (cb ^ ((r & 7) << 4)));
      }
#pragma unroll
      for (int ni = 0; ni < 4; ++ni) {
        int r = wcol + ni * 16 + lr;
        bf[ni] = *reinterpret_cast<const short8*>(Bb + r * 128 + (cb ^ ((r & 7) << 4)));
      }
#pragma unroll
      for (int mi = 0; mi < 2; ++mi)
#pragma unroll
        for (int ni = 0; ni < 4; ++ni)
          acc[mi][ni] = __builtin_amdgcn_mfma_f32_16x16x32_bf16(af[mi], bf[ni], acc[mi][ni], 0, 0, 0);
    }
    cur = nxt;
  }

#pragma unroll
  for (int mi = 0; mi < 2; ++mi) {
#pragma unroll
    for (int ni = 0; ni < 4; ++ni) {
#pragma unroll
      for (int r = 0; r < 4; ++r) {
        int m = arow0 + wrow + mi * 16 + irow + r;
        int j = bcol0 + wcol + ni * 16 + (l & 15);
        out[(size_t)m * DMODEL + j] = acc[mi][ni][r];
      }
    }
  }
}

// ---------------- flash attention: QBLK=128, KVBLK=128, 16 waves, 3-buffer ring ----------------
// waves = (qs 0..7: 16-row q-strip) x (g 0..1: 64-key half). Fixed-shift softmax.
// ONE barrier/iter with 3-deep ring. LDS 128KB: K[3][128][64], V[3][64][128], P[16][16][64].
__global__ __launch_bounds__(1024, 1) void attn(
    const short* __restrict__ qb, const short* __restrict__ kb,
    const short* __restrict__ vt, short* __restrict__ ob) {
  __shared__ short Ks[3][128 * 64];
  __shared__ short Vs[3][64 * 128];
  __shared__ short Ps[16][16 * 64];
  const int t = threadIdx.x;
  const int l = t & 63;
  const int w = t >> 6;                 // 0..15
  const int qs = w & 7;                 // q strip (16 rows)
  const int g  = w >> 3;                // key group (64-key half)
  const int id  = blockIdx.x;
  const int xcd = id & 7;
  const int bh  = xcd + 8 * (id >> 6);  // 4 heads per XCD
  const int qy  = (id >> 3) & 7;        // fold pair index 0..7
  const short* Q  = qb + (size_t)bh * NSEQ * HD;
  const short* Kg = kb + (size_t)bh * NSEQ * HD;
  const short* Vg = vt + (size_t)bh * HD * NSEQ;
  const int b = bh >> 4, h = bh & 15;

  const int trk = t >> 3;               // K staging row 0..127
  const int ck  = (t & 7) ^ ((t >> 3) & 7);
  const int trv = t >> 4;               // V staging row 0..63
  const int cv  = (t & 15) ^ ((t >> 4) & 15);
  const int irow = (l >> 4) << 2;
  const short8 ones = {(short)0x3F80, (short)0x3F80, (short)0x3F80, (short)0x3F80,
                       (short)0x3F80, (short)0x3F80, (short)0x3F80, (short)0x3F80};

  auto STAGEA = [&](int tile, int buf) {   // 2 loads/thread (1024 thr cover K+V)
    int j0 = tile * 128;
    load_lds16(Kg + (size_t)(j0 + trk) * HD + ck * 8, &Ks[buf][t * 8]);
    load_lds16(Vg + (size_t)trv * NSEQ + j0 + cv * 8, &Vs[buf][t * 8]);
  };

  int cur = 0;
  for (int pass = 0; pass < 2; ++pass) {
    const int qt = pass ? (15 - qy) : qy;     // q-tile of 128 rows
    const int q0 = qt * 128;
    const int nt = qt + 1;                    // 128-key tiles this pass

    asm volatile("s_barrier" ::: "memory");   // scratch + ring free before restage
    STAGEA(0, cur);

    short8 qf[2];
    {
      int qrow = q0 + qs * 16 + (l & 15);
#pragma unroll
      for (int ks = 0; ks < 2; ++ks)
        qf[ks] = *reinterpret_cast<const short8*>(Q + (size_t)qrow * HD + ks * 32 + (l >> 4) * 8);
    }

    f32x4 ao[4];
#pragma unroll
    for (int dt = 0; dt < 4; ++dt) ao[dt] = f32x4{0.f, 0.f, 0.f, 0.f};
    f32x4 accl = f32x4{0.f, 0.f, 0.f, 0.f};

    for (int tile = 0; tile < nt; ++tile) {
      const int nxt = (cur == 2) ? 0 : cur + 1;
      if (tile + 1 < nt) {
        STAGEA(tile + 1, nxt);
        asm volatile("s_waitcnt vmcnt(2)" ::: "memory");   // buf[cur]'s 2 landed
      } else {
        asm volatile("s_waitcnt vmcnt(0)" ::: "memory");
      }
      asm volatile("s_barrier" ::: "memory");              // all waves' buf[cur] ready

      const char* Kb = reinterpret_cast<const char*>(&Ks[cur][0]);
      const char* Vb = reinterpret_cast<const char*>(&Vs[cur][0]);

      // S = Q K^T over this wave's 64-key half (log2 domain via Q pre-scale)
      f32x4 sc[4];
#pragma unroll
      for (int jt = 0; jt < 4; ++jt) sc[jt] = f32x4{0.f, 0.f, 0.f, 0.f};
#pragma unroll
      for (int ks = 0; ks < 2; ++ks) {
        const int cb = ks * 64 + ((l >> 4) * 16);
#pragma unroll
        for (int jt = 0; jt < 4; ++jt) {
          int kr = g * 64 + jt * 16 + (l & 15);
          short8 kf = *reinterpret_cast<const short8*>(Kb + kr * 128 + (cb ^ ((kr & 7) << 4)));
          sc[jt] = __builtin_amdgcn_mfma_f32_16x16x32_bf16(qf[ks], kf, sc[jt], 0, 0, 0);
        }
      }

      if (tile == nt - 1) {                 // diagonal tile: mask j_g > i_g
        const int j0 = tile * 128 + g * 64;
#pragma unroll
        for (int jt = 0; jt < 4; ++jt)
#pragma unroll
          for (int r = 0; r < 4; ++r) {
            int i_g = q0 + qs * 16 + irow + r;
            int j_g = j0 + jt * 16 + (l & 15);
            if (j_g > i_g) sc[jt][r] = -1e30f;
          }
      }

      // P = exp2(S), bf16 truncate, to per-wave swizzled LDS [16][64]
#pragma unroll
      for (int jt = 0; jt < 4; ++jt) {
#pragma unroll
        for (int r = 0; r < 4; ++r) {
          float p = __builtin_amdgcn_exp2f(sc[jt][r]);
          int i = irow + r;
          int jj = jt * 16 + (l & 15);
          Ps[w][i * 64 + (jj ^ ((i & 7) << 3))] =
              (short)(__builtin_bit_cast(unsigned, p) >> 16);
        }
      }

      // O += P*V ; row-sum += P*ones  (64 keys = 2 slices of 32)
#pragma unroll
      for (int ks2 = 0; ks2 < 2; ++ks2) {
        const int cb = ks2 * 64 + ((l >> 4) * 16);
        int pr = l & 15;
        short8 pf = *reinterpret_cast<const short8*>(
            reinterpret_cast<const char*>(&Ps[w][0]) + pr * 128 + (cb ^ ((pr & 7) << 4)));
        accl = __builtin_amdgcn_mfma_f32_16x16x32_bf16(pf, ones, accl, 0, 0, 0);
#pragma unroll
        for (int dt = 0; dt < 4; ++dt) {
          int vr = dt * 16 + (l & 15);
          short8 vf = *reinterpret_cast<const short8*>(
              Vb + vr * 256 + ((g * 128 + cb) ^ ((vr & 15) << 4)));
          ao[dt] = __builtin_amdgcn_mfma_f32_16x16x32_bf16(pf, vf, ao[dt], 0, 0, 0);
        }
      }
      cur = nxt;
    }
    asm volatile("s_barrier" ::: "memory");   // all waves done reading the ring

    // ---- cross-group reduction (fixed-shift: partials just add) ----
    float* Opart = reinterpret_cast<float*>(&Ks[0][0]);
    float* Apart = reinterpret_cast<float*>(&Vs[0][0]);   // 8 x 16 f32
    const int cswz = ((l >> 4) & 1) << 4;
    if (g == 1) {
#pragma unroll
      for (int dt = 0; dt < 4; ++dt)
#pragma unroll
        for (int r = 0; r < 4; ++r)
          Opart[qs * 1024 + (irow + r) * 64 + ((dt * 16 + (l & 15)) ^ cswz)] = ao[dt][r];
      if ((l & 15) == 0)
#pragma unroll
        for (int r = 0; r < 4; ++r)
          Apart[qs * 16 + irow + r] = accl[r];
    }
    asm volatile("s_barrier" ::: "memory");
    if (g == 0) {
#pragma unroll
      for (int dt = 0; dt < 4; ++dt)
#pragma unroll
        for (int r = 0; r < 4; ++r)
          ao[dt][r] += Opart[qs * 1024 + (irow + r) * 64 + ((dt * 16 + (l & 15)) ^ cswz)];
#pragma unroll
      for (int r = 0; r < 4; ++r)
        accl[r] += Apart[qs * 16 + irow + r];
#pragma unroll
      for (int dt = 0; dt < 4; ++dt)
#pragma unroll
        for (int r = 0; r < 4; ++r) {
          int n = q0 + qs * 16 + irow + r;
          int col = h * 64 + dt * 16 + (l & 15);
          ob[((size_t)b * NSEQ + n) * DMODEL + col] = f2b(ao[dt][r] / accl[r]);
        }
    }
  }
}

// ---------------- launch ----------------
extern "C" void kernel_launch(void* const* d_in, const int* in_sizes, int n_in,
                              void* d_out, int out_size, void* d_ws, size_t ws_size,
                              hipStream_t stream) {
  const float* x  = (const float*)d_in[0];
  const float* Wq = (const float*)d_in[1];
  const float* Wk = (const float*)d_in[2];
  const float* Wv = (const float*)d_in[3];
  const float* Wo = (const float*)d_in[4];
  const int*   pos = (const int*)d_in[5];
  float* out = (float*)d_out;
  char* ws = (char*)d_ws;

  short* xb  = (short*)(ws);
  short* wqb = (short*)(ws + ((size_t)8  << 20));
  short* wkb = (short*)(ws + ((size_t)10 << 20));
  short* wvb = (short*)(ws + ((size_t)12 << 20));
  short* wob = (short*)(ws + ((size_t)14 << 20));
  short* qb  = (short*)(ws + ((size_t)16 << 20));
  short* kb  = (short*)(ws + ((size_t)24 << 20));
  short* vt  = (short*)(ws + ((size_t)32 << 20));
  short* ob  = (short*)(ws + ((size_t)40 << 20));
  float* cs  = (float*)(ws + ((size_t)48 << 20));

  cvt_all<<<2048, 256, 0, stream>>>(x, Wq, Wk, Wv, Wo, pos, xb, wqb, wkb, wvb, wob, cs);
  gemm_qkv3<<<256, 512, 0, stream>>>(xb, wqb, wkb, wvb, cs, qb, kb, vt);
  attn<<<256, 1024, 0, stream>>>(qb, kb, vt, ob);
  gemm_out<<<512, 256, 0, stream>>>(ob, wob, out);
}

// Round 29
// 89.117 us; speedup vs baseline: 1.1677x; 1.0397x over previous
//
#include <hip/hip_runtime.h>

// Problem constants (B=2, N=2048, d_model=1024, H=16, D=64)
#define DMODEL 1024
#define NSEQ   2048
#define BSZ    2
#define NH     16
#define HD     64
#define MROWS  (BSZ*NSEQ)   // 4096

using short8 = __attribute__((ext_vector_type(8))) short;
using f32x4  = __attribute__((ext_vector_type(4))) float;

__device__ __forceinline__ short f2b(float f) {
  unsigned u = __builtin_bit_cast(unsigned, f);
  u += 0x7fffu + ((u >> 16) & 1u);          // RNE
  return (short)(u >> 16);
}

__device__ __forceinline__ void load_lds16(const void* g, void* l) {
  __builtin_amdgcn_global_load_lds((const __attribute__((address_space(1))) unsigned int*)g,
                                   (__attribute__((address_space(3))) unsigned int*)l,
                                   16, 0, 0);
}

// ---------------- fused fp32->bf16 conversion (x, 4 weights) + RoPE table ----------------
__global__ void cvt_all(const float* __restrict__ x,  const float* __restrict__ Wq,
                        const float* __restrict__ Wk, const float* __restrict__ Wv,
                        const float* __restrict__ Wo, const int* __restrict__ pos,
                        short* __restrict__ xb,  short* __restrict__ wqb,
                        short* __restrict__ wkb, short* __restrict__ wvb,
                        short* __restrict__ wob, float* __restrict__ cs) {
  const int NX  = (BSZ * NSEQ * DMODEL) / 4;   // 1,048,576 float4s
  const int NW  = (DMODEL * DMODEL) / 4;       // 262,144 = 2^18
  const int NCV = NX + 4 * NW;
  const int TOT = NCV + NSEQ * 32;
  for (int i = blockIdx.x * blockDim.x + threadIdx.x; i < TOT; i += gridDim.x * blockDim.x) {
    if (i < NCV) {
      const float* src; short* dst; int off;
      if (i < NX) { src = x; dst = xb; off = i; }
      else {
        int j = i - NX; int s = j >> 18; off = j & (NW - 1);
        src = (s == 0) ? Wq : (s == 1) ? Wk : (s == 2) ? Wv : Wo;
        dst = (s == 0) ? wqb : (s == 1) ? wkb : (s == 2) ? wvb : wob;
      }
      float4 v = reinterpret_cast<const float4*>(src)[off];
      short4 r;
      r.x = f2b(v.x); r.y = f2b(v.y); r.z = f2b(v.z); r.w = f2b(v.w);
      reinterpret_cast<short4*>(dst)[off] = r;
    } else {
      int idx = i - NCV;
      int n = idx >> 5, p = idx & 31;
      float inv = powf(10000.0f, -(float)(2 * p) / 64.0f);
      float ang = (float)pos[n] * inv;
      cs[idx * 2]     = cosf(ang);
      cs[idx * 2 + 1] = sinf(ang);
    }
  }
}

// ============ Fused QKV projection: 128x64x3 tiles, 2 blocks/CU ============
// Grid 512 = 32 row-panels (id&31; id&7 -> XCD keeps 4 A-panels L2-local)
// x 16 col-panels of 64. 256 thr = 4 waves (2r x 2c): wave = 64 rows x 32
// cols x {Q,K,V} (same 24 MFMA/K-step density as the proven 8-wave kernel).
// LDS 80KB -> 2 blocks/CU co-resident (m114 convoy overlap; the occupancy
// lever validated on gemm_out). 2-buffer, counted vmcnt(10), 2 barriers/iter.
// Q pre-scaled by (1/8)*log2e so attn computes P = exp2(S) directly.
__global__ __launch_bounds__(256, 2) void gemm_qkv3(
    const short* __restrict__ xb,
    const short* __restrict__ wq, const short* __restrict__ wk, const short* __restrict__ wv,
    const float* __restrict__ cs,
    short* __restrict__ qb, short* __restrict__ kb, short* __restrict__ vt) {
  __shared__ short Al[2][128 * 64];     // 2 x 16KB
  __shared__ short Bl[2][3][64 * 64];   // 2 x 24KB

  const int t   = threadIdx.x;
  const int l   = t & 63;
  const int wid = t >> 6;            // 0..3
  const int wr  = (wid >> 1) * 64;   // wave row-offset: 0 / 64
  const int wc  = (wid & 1) * 32;    // wave col-offset: 0 / 32

  const int id = blockIdx.x;         // 0..511; id&7 -> XCD
  const int bx = id & 31;
  const int np = id >> 5;            // 0..15
  const int arow0 = bx * 128;
  const int bcol0 = np * 64;

  const int tr = t >> 3;             // 0..31
  const int c8 = (t & 7) ^ ((t >> 3) & 7);   // rows step by 32 -> row&7 invariant
  const short* W3[3] = {wq, wk, wv};

  auto STAGE = [&](int kt, int buf) {  // 10 loads/thread: A x4 + 3W x2
#pragma unroll
    for (int is = 0; is < 4; ++is)
      load_lds16(xb + (size_t)(arow0 + tr + is * 32) * DMODEL + kt * 64 + c8 * 8,
                 &Al[buf][is * 2048 + t * 8]);
#pragma unroll
    for (int p = 0; p < 3; ++p)
#pragma unroll
      for (int is = 0; is < 2; ++is)
        load_lds16(W3[p] + (size_t)(bcol0 + tr + is * 32) * DMODEL + kt * 64 + c8 * 8,
                   &Bl[buf][p][is * 2048 + t * 8]);
  };

  f32x4 acc[3][4][2];
#pragma unroll
  for (int p = 0; p < 3; ++p)
#pragma unroll
    for (int mi = 0; mi < 4; ++mi)
#pragma unroll
      for (int ni = 0; ni < 2; ++ni) acc[p][mi][ni] = f32x4{0.f, 0.f, 0.f, 0.f};

  const int lr  = l & 15;
  const int lcb = (l >> 4) << 4;

  STAGE(0, 0);
  int cur = 0;

  for (int kt = 0; kt < DMODEL / 64; ++kt) {
    if (kt + 1 < DMODEL / 64) {
      STAGE(kt + 1, cur ^ 1);                           // 10 newer loads in flight
      asm volatile("s_waitcnt vmcnt(10)" ::: "memory"); // tile kt's 10 landed
    } else {
      asm volatile("s_waitcnt vmcnt(0)" ::: "memory");
    }
    asm volatile("s_barrier" ::: "memory");             // publish buf[cur]

    const char* Ab = reinterpret_cast<const char*>(&Al[cur][0]);
#pragma unroll
    for (int ks = 0; ks < 2; ++ks) {
      const int cb = ks * 64 + lcb;
      short8 af[4];
#pragma unroll
      for (int mi = 0; mi < 4; ++mi) {
        int r = wr + mi * 16 + lr;
        af[mi] = *reinterpret_cast<const short8*>(Ab + r * 128 + (cb ^ ((r & 7) << 4)));
      }
#pragma unroll
      for (int p = 0; p < 3; ++p) {
        const char* Bb = reinterpret_cast<const char*>(&Bl[cur][p][0]);
        short8 bf[2];
#pragma unroll
        for (int ni = 0; ni < 2; ++ni) {
          int r = wc + ni * 16 + lr;
          bf[ni] = *reinterpret_cast<const short8*>(Bb + r * 128 + (cb ^ ((r & 7) << 4)));
        }
#pragma unroll
        for (int mi = 0; mi < 4; ++mi)
#pragma unroll
          for (int ni = 0; ni < 2; ++ni)
            acc[p][mi][ni] = __builtin_amdgcn_mfma_f32_16x16x32_bf16(af[mi], bf[ni], acc[p][mi][ni], 0, 0, 0);
      }
    }
    asm volatile("s_barrier" ::: "memory");             // reads done before next overwrite
    cur ^= 1;
  }

  // ---------- epilogue: RoPE + scatter for Q,K; transpose-scatter V
  const int irow = (l >> 4) << 2;
#pragma unroll
  for (int p = 0; p < 3; ++p) {
#pragma unroll
    for (int mi = 0; mi < 4; ++mi) {
#pragma unroll
      for (int ni = 0; ni < 2; ++ni) {
#pragma unroll
        for (int r = 0; r < 4; ++r) {
          float v = acc[p][mi][ni][r];
          int m = arow0 + wr + mi * 16 + irow + r;
          int j = bcol0 + wc + ni * 16 + (l & 15);
          int n = m & (NSEQ - 1);
          int b = m >> 11;
          int h = j >> 6, d = j & 63, pp = d >> 1;
          float pv = __shfl_xor(v, 1);              // partner column (j^1), same row
          if (p < 2) {
            float c = cs[(n * 32 + pp) * 2];
            float s = cs[(n * 32 + pp) * 2 + 1];
            float res = (d & 1) ? (pv * s + v * c) : (v * c - pv * s);
            if (p == 0) res *= 0.180336880f;        // (1/sqrt(64)) * log2(e): P = exp2(S)
            short* dst = (p == 0) ? qb : kb;
            dst[(((size_t)(b * NH + h)) * NSEQ + n) * HD + d] = f2b(res);
          } else {
            vt[(((size_t)(b * NH + h)) * HD + d) * NSEQ + n] = f2b(v);
          }
        }
      }
    }
  }
}

// ---------------- output projection: 64x128 tiles, 3-buffer ring, 1 barrier/iter ----------------
__global__ __launch_bounds__(256, 2) void gemm_out(
    const short* __restrict__ ob, const short* __restrict__ wo, float* __restrict__ out) {
  __shared__ short As[3 * 64 * 64];    // [3][4096] shorts, rows 128B
  __shared__ short Bs[3 * 128 * 64];   // [3][8192] shorts, rows 128B
  const int t = threadIdx.x;
  const int l = t & 63;
  const int w4 = t >> 6;               // 0..3
  const int wrow = (w4 >> 1) * 32;
  const int wcol = (w4 & 1) * 64;
  const int id = blockIdx.x;           // id&7 -> XCD: 8 row-panels/XCD (A L2-local)
  const int arow0 = (id & 63) * 64;
  const int bcol0 = (id >> 6) * 128;

  const int tr = t >> 3;               // 0..31
  const int c8 = (t & 7) ^ (tr & 7);   // rows step by 32 -> row&7 invariant

  auto STAGE = [&](int kt, int buf) {  // 6 loads/thread: A x2 + B x4
#pragma unroll
    for (int is = 0; is < 2; ++is)
      load_lds16(ob + (size_t)(arow0 + tr + is * 32) * DMODEL + kt * 64 + c8 * 8,
                 &As[buf * 4096 + is * 2048 + (t >> 6) * 512]);
#pragma unroll
    for (int is = 0; is < 4; ++is)
      load_lds16(wo + (size_t)(bcol0 + tr + is * 32) * DMODEL + kt * 64 + c8 * 8,
                 &Bs[buf * 8192 + is * 2048 + (t >> 6) * 512]);
  };

  f32x4 acc[2][4];
#pragma unroll
  for (int mi = 0; mi < 2; ++mi)
#pragma unroll
    for (int ni = 0; ni < 4; ++ni) acc[mi][ni] = f32x4{0.f, 0.f, 0.f, 0.f};

  const int lr  = l & 15;
  const int lcb = (l >> 4) << 4;
  const int irow = (l >> 4) << 2;

  STAGE(0, 0);
  int cur = 0;

  for (int kt = 0; kt < DMODEL / 64; ++kt) {
    const int nxt = (cur == 2) ? 0 : cur + 1;
    if (kt + 1 < DMODEL / 64) {
      STAGE(kt + 1, nxt);                              // 6 newer loads in flight
      asm volatile("s_waitcnt vmcnt(6)" ::: "memory"); // buf[cur]'s 6 landed
    } else {
      asm volatile("s_waitcnt vmcnt(0)" ::: "memory");
    }
    asm volatile("s_barrier" ::: "memory");            // all waves' buf[cur] ready

    const char* Ab = reinterpret_cast<const char*>(&As[cur * 4096]);
    const char* Bb = reinterpret_cast<const char*>(&Bs[cur * 8192]);
#pragma unroll
    for (int ks = 0; ks < 2; ++ks) {
      const int cb = ks * 64 + lcb;
      short8 af[2], bf[4];
#pragma unroll
      for (int mi = 0; mi < 2; ++mi) {
        int r = wrow + mi * 16 + lr;
        af[mi] = *reinterpret_cast<const short8*>(Ab + r * 128 + (cb ^ ((r & 7) << 4)));
      }
#pragma unroll
      for (int ni = 0; ni < 4; ++ni) {
        int r = wcol + ni * 16 + lr;
        bf[ni] = *reinterpret_cast<const short8*>(Bb + r * 128 + (cb ^ ((r & 7) << 4)));
      }
#pragma unroll
      for (int mi = 0; mi < 2; ++mi)
#pragma unroll
        for (int ni = 0; ni < 4; ++ni)
          acc[mi][ni] = __builtin_amdgcn_mfma_f32_16x16x32_bf16(af[mi], bf[ni], acc[mi][ni], 0, 0, 0);
    }
    cur = nxt;
  }

#pragma unroll
  for (int mi = 0; mi < 2; ++mi) {
#pragma unroll
    for (int ni = 0; ni < 4; ++ni) {
#pragma unroll
      for (int r = 0; r < 4; ++r) {
        int m = arow0 + wrow + mi * 16 + irow + r;
        int j = bcol0 + wcol + ni * 16 + (l & 15);
        out[(size_t)m * DMODEL + j] = acc[mi][ni][r];
      }
    }
  }
}

// ---------------- flash attention: QBLK=128, KVBLK=128, 16 waves, 3-buffer ring ----------------
// waves = (qs 0..7: 16-row q-strip) x (g 0..1: 64-key half). Fixed-shift softmax.
// ONE barrier/iter with 3-deep ring. LDS 128KB: K[3][128][64], V[3][64][128], P[16][16][64].
__global__ __launch_bounds__(1024, 1) void attn(
    const short* __restrict__ qb, const short* __restrict__ kb,
    const short* __restrict__ vt, short* __restrict__ ob) {
  __shared__ short Ks[3][128 * 64];
  __shared__ short Vs[3][64 * 128];
  __shared__ short Ps[16][16 * 64];
  const int t = threadIdx.x;
  const int l = t & 63;
  const int w = t >> 6;                 // 0..15
  const int qs = w & 7;                 // q strip (16 rows)
  const int g  = w >> 3;                // key group (64-key half)
  const int id  = blockIdx.x;
  const int xcd = id & 7;
  const int bh  = xcd + 8 * (id >> 6);  // 4 heads per XCD
  const int qy  = (id >> 3) & 7;        // fold pair index 0..7
  const short* Q  = qb + (size_t)bh * NSEQ * HD;
  const short* Kg = kb + (size_t)bh * NSEQ * HD;
  const short* Vg = vt + (size_t)bh * HD * NSEQ;
  const int b = bh >> 4, h = bh & 15;

  const int trk = t >> 3;               // K staging row 0..127
  const int ck  = (t & 7) ^ ((t >> 3) & 7);
  const int trv = t >> 4;               // V staging row 0..63
  const int cv  = (t & 15) ^ ((t >> 4) & 15);
  const int irow = (l >> 4) << 2;
  const short8 ones = {(short)0x3F80, (short)0x3F80, (short)0x3F80, (short)0x3F80,
                       (short)0x3F80, (short)0x3F80, (short)0x3F80, (short)0x3F80};

  auto STAGEA = [&](int tile, int buf) {   // 2 loads/thread (1024 thr cover K+V)
    int j0 = tile * 128;
    load_lds16(Kg + (size_t)(j0 + trk) * HD + ck * 8, &Ks[buf][t * 8]);
    load_lds16(Vg + (size_t)trv * NSEQ + j0 + cv * 8, &Vs[buf][t * 8]);
  };

  int cur = 0;
  for (int pass = 0; pass < 2; ++pass) {
    const int qt = pass ? (15 - qy) : qy;     // q-tile of 128 rows
    const int q0 = qt * 128;
    const int nt = qt + 1;                    // 128-key tiles this pass

    asm volatile("s_barrier" ::: "memory");   // scratch + ring free before restage
    STAGEA(0, cur);

    short8 qf[2];
    {
      int qrow = q0 + qs * 16 + (l & 15);
#pragma unroll
      for (int ks = 0; ks < 2; ++ks)
        qf[ks] = *reinterpret_cast<const short8*>(Q + (size_t)qrow * HD + ks * 32 + (l >> 4) * 8);
    }

    f32x4 ao[4];
#pragma unroll
    for (int dt = 0; dt < 4; ++dt) ao[dt] = f32x4{0.f, 0.f, 0.f, 0.f};
    f32x4 accl = f32x4{0.f, 0.f, 0.f, 0.f};

    for (int tile = 0; tile < nt; ++tile) {
      const int nxt = (cur == 2) ? 0 : cur + 1;
      if (tile + 1 < nt) {
        STAGEA(tile + 1, nxt);
        asm volatile("s_waitcnt vmcnt(2)" ::: "memory");   // buf[cur]'s 2 landed
      } else {
        asm volatile("s_waitcnt vmcnt(0)" ::: "memory");
      }
      asm volatile("s_barrier" ::: "memory");              // all waves' buf[cur] ready

      const char* Kb = reinterpret_cast<const char*>(&Ks[cur][0]);
      const char* Vb = reinterpret_cast<const char*>(&Vs[cur][0]);

      // S = Q K^T over this wave's 64-key half (log2 domain via Q pre-scale)
      f32x4 sc[4];
#pragma unroll
      for (int jt = 0; jt < 4; ++jt) sc[jt] = f32x4{0.f, 0.f, 0.f, 0.f};
#pragma unroll
      for (int ks = 0; ks < 2; ++ks) {
        const int cb = ks * 64 + ((l >> 4) * 16);
#pragma unroll
        for (int jt = 0; jt < 4; ++jt) {
          int kr = g * 64 + jt * 16 + (l & 15);
          short8 kf = *reinterpret_cast<const short8*>(Kb + kr * 128 + (cb ^ ((kr & 7) << 4)));
          sc[jt] = __builtin_amdgcn_mfma_f32_16x16x32_bf16(qf[ks], kf, sc[jt], 0, 0, 0);
        }
      }

      if (tile == nt - 1) {                 // diagonal tile: mask j_g > i_g
        const int j0 = tile * 128 + g * 64;
#pragma unroll
        for (int jt = 0; jt < 4; ++jt)
#pragma unroll
          for (int r = 0; r < 4; ++r) {
            int i_g = q0 + qs * 16 + irow + r;
            int j_g = j0 + jt * 16 + (l & 15);
            if (j_g > i_g) sc[jt][r] = -1e30f;
          }
      }

      // P = exp2(S), bf16 truncate, to per-wave swizzled LDS [16][64]
#pragma unroll
      for (int jt = 0; jt < 4; ++jt) {
#pragma unroll
        for (int r = 0; r < 4; ++r) {
          float p = __builtin_amdgcn_exp2f(sc[jt][r]);
          int i = irow + r;
          int jj = jt * 16 + (l & 15);
          Ps[w][i * 64 + (jj ^ ((i & 7) << 3))] =
              (short)(__builtin_bit_cast(unsigned, p) >> 16);
        }
      }

      // O += P*V ; row-sum += P*ones  (64 keys = 2 slices of 32)
#pragma unroll
      for (int ks2 = 0; ks2 < 2; ++ks2) {
        const int cb = ks2 * 64 + ((l >> 4) * 16);
        int pr = l & 15;
        short8 pf = *reinterpret_cast<const short8*>(
            reinterpret_cast<const char*>(&Ps[w][0]) + pr * 128 + (cb ^ ((pr & 7) << 4)));
        accl = __builtin_amdgcn_mfma_f32_16x16x32_bf16(pf, ones, accl, 0, 0, 0);
#pragma unroll
        for (int dt = 0; dt < 4; ++dt) {
          int vr = dt * 16 + (l & 15);
          short8 vf = *reinterpret_cast<const short8*>(
              Vb + vr * 256 + ((g * 128 + cb) ^ ((vr & 15) << 4)));
          ao[dt] = __builtin_amdgcn_mfma_f32_16x16x32_bf16(pf, vf, ao[dt], 0, 0, 0);
        }
      }
      cur = nxt;
    }
    asm volatile("s_barrier" ::: "memory");   // all waves done reading the ring

    // ---- cross-group reduction (fixed-shift: partials just add) ----
    float* Opart = reinterpret_cast<float*>(&Ks[0][0]);
    float* Apart = reinterpret_cast<float*>(&Vs[0][0]);   // 8 x 16 f32
    const int cswz = ((l >> 4) & 1) << 4;
    if (g == 1) {
#pragma unroll
      for (int dt = 0; dt < 4; ++dt)
#pragma unroll
        for (int r = 0; r < 4; ++r)
          Opart[qs * 1024 + (irow + r) * 64 + ((dt * 16 + (l & 15)) ^ cswz)] = ao[dt][r];
      if ((l & 15) == 0)
#pragma unroll
        for (int r = 0; r < 4; ++r)
          Apart[qs * 16 + irow + r] = accl[r];
    }
    asm volatile("s_barrier" ::: "memory");
    if (g == 0) {
#pragma unroll
      for (int dt = 0; dt < 4; ++dt)
#pragma unroll
        for (int r = 0; r < 4; ++r)
          ao[dt][r] += Opart[qs * 1024 + (irow + r) * 64 + ((dt * 16 + (l & 15)) ^ cswz)];
#pragma unroll
      for (int r = 0; r < 4; ++r)
        accl[r] += Apart[qs * 16 + irow + r];
#pragma unroll
      for (int dt = 0; dt < 4; ++dt)
#pragma unroll
        for (int r = 0; r < 4; ++r) {
          int n = q0 + qs * 16 + irow + r;
          int col = h * 64 + dt * 16 + (l & 15);
          ob[((size_t)b * NSEQ + n) * DMODEL + col] = f2b(ao[dt][r] / accl[r]);
        }
    }
  }
}

// ---------------- launch ----------------
extern "C" void kernel_launch(void* const* d_in, const int* in_sizes, int n_in,
                              void* d_out, int out_size, void* d_ws, size_t ws_size,
                              hipStream_t stream) {
  const float* x  = (const float*)d_in[0];
  const float* Wq = (const float*)d_in[1];
  const float* Wk = (const float*)d_in[2];
  const float* Wv = (const float*)d_in[3];
  const float* Wo = (const float*)d_in[4];
  const int*   pos = (const int*)d_in[5];
  float* out = (float*)d_out;
  char* ws = (char*)d_ws;

  short* xb  = (short*)(ws);
  short* wqb = (short*)(ws + ((size_t)8  << 20));
  short* wkb = (short*)(ws + ((size_t)10 << 20));
  short* wvb = (short*)(ws + ((size_t)12 << 20));
  short* wob = (short*)(ws + ((size_t)14 << 20));
  short* qb  = (short*)(ws + ((size_t)16 << 20));
  short* kb  = (short*)(ws + ((size_t)24 << 20));
  short* vt  = (short*)(ws + ((size_t)32 << 20));
  short* ob  = (short*)(ws + ((size_t)40 << 20));
  float* cs  = (float*)(ws + ((size_t)48 << 20));

  cvt_all<<<2048, 256, 0, stream>>>(x, Wq, Wk, Wv, Wo, pos, xb, wqb, wkb, wvb, wob, cs);
  gemm_qkv3<<<512, 256, 0, stream>>>(xb, wqb, wkb, wvb, cs, qb, kb, vt);
  attn<<<256, 1024, 0, stream>>>(qb, kb, vt, ob);
  gemm_out<<<512, 256, 0, stream>>>(ob, wob, out);
}